// Round 4
// baseline (11270.245 us; speedup 1.0000x reference)
//
#include <hip/hip_runtime.h>
#include <math.h>

#define NN 512
#define DD 8192

// ---------------- row-norm scales: scale[m][r] = 1 / max(||row||, 1e-6) ----------------
__global__ __launch_bounds__(256) void norm_kernel(
    const float* __restrict__ a0, const float* __restrict__ a1,
    const float* __restrict__ a2, float* __restrict__ scales) {
  const float* mats[3] = {a0, a1, a2};
  const int m = blockIdx.y;
  const int row = blockIdx.x;
  const float* x = mats[m] + (size_t)row * DD;
  const int tid = threadIdx.x;
  float s = 0.f;
  for (int k = tid * 4; k < DD; k += 256 * 4) {
    const float4 v = *(const float4*)(x + k);
    s += v.x * v.x + v.y * v.y + v.z * v.z + v.w * v.w;
  }
#pragma unroll
  for (int off = 32; off > 0; off >>= 1) s += __shfl_down(s, off);
  __shared__ float ws[4];
  if ((tid & 63) == 0) ws[tid >> 6] = s;
  __syncthreads();
  if (tid == 0) {
    const float t = ws[0] + ws[1] + ws[2] + ws[3];
    scales[m * NN + row] = 1.0f / fmaxf(sqrtf(t), 1e-6f);
  }
}

// ---------------- cost_p = 1 - (A B^T) * sa * sb, p: (0:1->2, 1:2->3, 2:3->1) ----------
__global__ __launch_bounds__(256) void cost_gemm_kernel(
    const float* __restrict__ a0, const float* __restrict__ a1,
    const float* __restrict__ a2, const float* __restrict__ scales,
    float* __restrict__ cost_all) {
  const float* mats[3] = {a0, a1, a2};
  const int p = blockIdx.z;
  const int pA = p, pB = (p + 1) % 3;
  const float* A = mats[pA];
  const float* B = mats[pB];
  float* C = cost_all + (size_t)p * NN * NN;

  __shared__ float lds_a[32 * 64];
  __shared__ float lds_b[32 * 64];

  const int tid = threadIdx.x;
  const int rowBase = blockIdx.y * 64;
  const int colBase = blockIdx.x * 64;

  const int lr = tid & 63;   // row within tile for staging
  const int lq = tid >> 6;   // 0..3

  const float* Arow = A + (size_t)(rowBase + lr) * DD;
  const float* Brow = B + (size_t)(colBase + lr) * DD;

  float acc[4][4];
#pragma unroll
  for (int i = 0; i < 4; ++i)
#pragma unroll
    for (int j = 0; j < 4; ++j) acc[i][j] = 0.f;

  const int tx = tid & 15, ty = tid >> 4;

  for (int kb = 0; kb < DD; kb += 32) {
#pragma unroll
    for (int qq = 0; qq < 2; ++qq) {
      const int q = lq + qq * 4;  // 0..7, covers k offsets q*4..q*4+3
      const float4 av = *(const float4*)(Arow + kb + q * 4);
      const float4 bv = *(const float4*)(Brow + kb + q * 4);
      lds_a[(q * 4 + 0) * 64 + lr] = av.x;
      lds_a[(q * 4 + 1) * 64 + lr] = av.y;
      lds_a[(q * 4 + 2) * 64 + lr] = av.z;
      lds_a[(q * 4 + 3) * 64 + lr] = av.w;
      lds_b[(q * 4 + 0) * 64 + lr] = bv.x;
      lds_b[(q * 4 + 1) * 64 + lr] = bv.y;
      lds_b[(q * 4 + 2) * 64 + lr] = bv.z;
      lds_b[(q * 4 + 3) * 64 + lr] = bv.w;
    }
    __syncthreads();
#pragma unroll
    for (int k = 0; k < 32; ++k) {
      const float4 a4 = *(const float4*)(&lds_a[k * 64 + ty * 4]);
      const float4 b4 = *(const float4*)(&lds_b[k * 64 + tx * 4]);
      const float as0[4] = {a4.x, a4.y, a4.z, a4.w};
      const float bs0[4] = {b4.x, b4.y, b4.z, b4.w};
#pragma unroll
      for (int ii = 0; ii < 4; ++ii)
#pragma unroll
        for (int jj = 0; jj < 4; ++jj)
          acc[ii][jj] = fmaf(as0[ii], bs0[jj], acc[ii][jj]);
    }
    __syncthreads();
  }

#pragma unroll
  for (int ii = 0; ii < 4; ++ii) {
    const int gr = rowBase + ty * 4 + ii;
    const float sa = scales[pA * NN + gr];
#pragma unroll
    for (int jj = 0; jj < 4; ++jj) {
      const int gc = colBase + tx * 4 + jj;
      const float sb = scales[pB * NN + gc];
      C[gr * NN + gc] = 1.0f - acc[ii][jj] * sa * sb;
    }
  }
}

// ---------------- exact LAP: LAPJV init (colred + RT + 2xARR) + SAP, one wave ----------
// Lane t owns columns/rows 8t..8t+7. Final assignment equals the reference's (unique
// optimum for generic data). All dual arithmetic in f64 on exact f32 costs; u derived
// at init end as exactly c[i][x[i]] - v[x[i]] => tight matched edges, reduced costs
// >= 0 (within ulp), so the Round-3 SAP phase code is valid from this warm start.

// bijective LDS index swizzle: owner-lane accesses (stride 8) become conflict-free
__device__ __forceinline__ int SW(int c) { return ((c & 7) << 6) | (c >> 3); }

// full-wave (64-lane) u32 min via DPP; returns broadcast scalar
__device__ __forceinline__ unsigned wave_min_u32(unsigned x) {
  int t;
  t = __builtin_amdgcn_update_dpp((int)x, (int)x, 0x111, 0xf, 0xf, false);  // row_shr:1
  x = ((unsigned)t < x) ? (unsigned)t : x;
  t = __builtin_amdgcn_update_dpp((int)x, (int)x, 0x112, 0xf, 0xf, false);  // row_shr:2
  x = ((unsigned)t < x) ? (unsigned)t : x;
  t = __builtin_amdgcn_update_dpp((int)x, (int)x, 0x114, 0xf, 0xf, false);  // row_shr:4
  x = ((unsigned)t < x) ? (unsigned)t : x;
  t = __builtin_amdgcn_update_dpp((int)x, (int)x, 0x118, 0xf, 0xf, false);  // row_shr:8
  x = ((unsigned)t < x) ? (unsigned)t : x;
  t = __builtin_amdgcn_update_dpp((int)x, (int)x, 0x142, 0xf, 0xf, false);  // row_bcast:15
  x = ((unsigned)t < x) ? (unsigned)t : x;
  t = __builtin_amdgcn_update_dpp((int)x, (int)x, 0x143, 0xf, 0xf, false);  // row_bcast:31
  x = ((unsigned)t < x) ? (unsigned)t : x;
  return (unsigned)__builtin_amdgcn_readlane((int)x, 63);
}

__device__ __forceinline__ double readlane_f64(double x, int lane) {
  const long long b = __double_as_longlong(x);
  const int lo = __builtin_amdgcn_readlane((int)(b & 0xffffffffLL), lane);
  const int hi = __builtin_amdgcn_readlane((int)(b >> 32), lane);
  return __longlong_as_double(((long long)hi << 32) | (unsigned long long)(unsigned)lo);
}

__device__ __forceinline__ unsigned long long f64key(double x) {
  const long long b = __double_as_longlong(x);
  return (b < 0) ? ~(unsigned long long)b
                 : ((unsigned long long)b | 0x8000000000000000ULL);
}

// exact wave argmin of f64 x; lowest lane on exact ties; returns lane, sets *mv
__device__ __forceinline__ int wave_argmin_f64(double x, double* mv) {
  const unsigned long long k = f64key(x);
  const unsigned hi = (unsigned)(k >> 32), lo = (unsigned)k;
  const unsigned minhi = wave_min_u32(hi);
  unsigned long long bal = __ballot(hi == minhi);
  int lane;
  if (__popcll(bal) == 1) {
    lane = __ffsll(bal) - 1;
  } else {
    const unsigned lo2 = (hi == minhi) ? lo : 0xFFFFFFFFu;
    const unsigned minlo = wave_min_u32(lo2);
    bal = __ballot((hi == minhi) && (lo == minlo));
    lane = __ffsll(bal) - 1;
  }
  *mv = readlane_f64(x, lane);
  return lane;
}

__global__ __launch_bounds__(64) void lap_kernel(
    const float* __restrict__ cost_all, float* __restrict__ out) {
  const int p = blockIdx.x;
  const float* cost = cost_all + (size_t)p * NN * NN;
  float* outp = out + (size_t)p * NN * NN;
  const int tid = threadIdx.x;  // 0..63

  __shared__ double sh_u[NN];        // u[row] at SW(row)
  __shared__ double sh_v[NN];        // v[col] at SW(col) (init phases)
  __shared__ double sh_shortest[NN]; // frozen shortest[col] at SW(col)
  __shared__ int sh_path[NN];        // path[col] at SW(col)
  __shared__ int sh_x[NN];           // col4row[row] at SW(row)
  __shared__ int sh_y[NN];           // row4col[col] at SW(col)
  __shared__ int sh_cnt[NN];         // colred argmin multiplicity per row
  __shared__ int sh_free[NN];        // free-row work list (plain indexing)

  const double INF = __builtin_inf();

#pragma unroll
  for (int q = 0; q < 8; ++q) {
    const int e = tid * 8 + q;
    sh_x[SW(e)] = -1;
    sh_y[SW(e)] = -1;
    sh_cnt[SW(e)] = 0;
  }
  __syncthreads();

  // ---- 1. column reduction: v[j] = min_i c[i][j], assign argmin rows (max-j wins,
  //         equivalent to lap.c descending-j first-come) ----
  float colv[8];
  int imin[8];
#pragma unroll
  for (int q = 0; q < 8; ++q) { colv[q] = __builtin_inff(); imin[q] = 0; }
  for (int i = 0; i < NN; i += 2) {
    const float4 a0 = *(const float4*)(cost + (size_t)i * NN + tid * 8);
    const float4 a1 = *(const float4*)(cost + (size_t)i * NN + tid * 8 + 4);
    const float4 b0 = *(const float4*)(cost + (size_t)(i + 1) * NN + tid * 8);
    const float4 b1 = *(const float4*)(cost + (size_t)(i + 1) * NN + tid * 8 + 4);
    const float fa[8] = {a0.x, a0.y, a0.z, a0.w, a1.x, a1.y, a1.z, a1.w};
    const float fb[8] = {b0.x, b0.y, b0.z, b0.w, b1.x, b1.y, b1.z, b1.w};
#pragma unroll
    for (int q = 0; q < 8; ++q) {
      if (fa[q] < colv[q]) { colv[q] = fa[q]; imin[q] = i; }
      if (fb[q] < colv[q]) { colv[q] = fb[q]; imin[q] = i + 1; }
    }
  }
#pragma unroll
  for (int q = 0; q < 8; ++q) {
    sh_v[SW(tid * 8 + q)] = (double)colv[q];
    atomicMax(&sh_x[SW(imin[q])], tid * 8 + q);
    atomicAdd(&sh_cnt[SW(imin[q])], 1);
  }
  __syncthreads();
#pragma unroll
  for (int q = 0; q < 8; ++q) {
    const int j = tid * 8 + q;
    sh_y[SW(j)] = (sh_x[SW(imin[q])] == j) ? imin[q] : -1;
  }
  __syncthreads();

  // ---- 2. reduction transfer: rows with exactly one argmin col ----
  for (int q0 = 0; q0 < 8; ++q0) {
    const bool rt = (sh_cnt[SW(tid * 8 + q0)] == 1);
    unsigned long long mask = __ballot(rt);
    while (mask) {
      const int lane = __ffsll(mask) - 1;
      mask &= mask - 1;
      const int i = lane * 8 + q0;     // uniform
      const int j1 = sh_x[SW(i)];      // uniform broadcast
      const float4 c0 = *(const float4*)(cost + (size_t)i * NN + tid * 8);
      const float4 c1 = *(const float4*)(cost + (size_t)i * NN + tid * 8 + 4);
      const float cf[8] = {c0.x, c0.y, c0.z, c0.w, c1.x, c1.y, c1.z, c1.w};
      double m = INF;
#pragma unroll
      for (int q = 0; q < 8; ++q) {
        const int col = tid * 8 + q;
        double h = (double)cf[q] - sh_v[SW(col)];
        if (col == j1) h = INF;
        m = fmin(m, h);
      }
      double gmin;
      (void)wave_argmin_f64(m, &gmin);
      if (tid == 0) sh_v[SW(j1)] = sh_v[SW(j1)] - gmin;
    }
  }
  __syncthreads();

  // ---- build free-row list (deterministic q-major order) ----
  int numfree = 0;
  for (int q0 = 0; q0 < 8; ++q0) {
    const int row = tid * 8 + q0;
    const bool fr = (sh_x[SW(row)] < 0);
    const unsigned long long mask = __ballot(fr);
    if (fr) {
      const int pos = numfree + (int)__popcll(mask & ((1ull << tid) - 1ull));
      sh_free[pos] = row;
    }
    numfree += (int)__popcll(mask);
  }
  __syncthreads();

  // ---- 3. augmenting row reduction, two passes (lap.c ARR) ----
  int nf = numfree;
  for (int pass = 0; pass < 2; ++pass) {
    int k = 0;
    const int prv = nf;
    nf = 0;
    int guard = 0;
    while (k < prv && ++guard < 5000) {
      const int i = sh_free[k];
      k++;
      const float4 c0 = *(const float4*)(cost + (size_t)i * NN + tid * 8);
      const float4 c1 = *(const float4*)(cost + (size_t)i * NN + tid * 8 + 4);
      const float cf[8] = {c0.x, c0.y, c0.z, c0.w, c1.x, c1.y, c1.z, c1.w};
      double um = (double)cf[0] - sh_v[SW(tid * 8)];
      int j1q = tid * 8;
      double us = INF;
      int j2q = tid * 8;
#pragma unroll
      for (int q = 1; q < 8; ++q) {
        const double h = (double)cf[q] - sh_v[SW(tid * 8 + q)];
        const int col = tid * 8 + q;
        if (h < us) {
          if (h >= um) { us = h; j2q = col; }
          else { us = um; j2q = j1q; um = h; j1q = col; }
        }
      }
      double g_umin;
      const int lane1 = wave_argmin_f64(um, &g_umin);
      const double su = (tid == lane1) ? us : um;
      double g_usub;
      const int lane2 = wave_argmin_f64(su, &g_usub);
      int j1 = __builtin_amdgcn_readlane(j1q, lane1);
      const int j2 = __builtin_amdgcn_readlane((lane2 == lane1) ? j2q : j1q, lane2);
      int i0 = sh_y[SW(j1)];
      const bool strict = g_umin < g_usub;
      if (strict) {
        if (tid == 0) sh_v[SW(j1)] = sh_v[SW(j1)] - (g_usub - g_umin);
      } else if (i0 >= 0) {
        j1 = j2;
        i0 = sh_y[SW(j1)];
      }
      if (tid == 0) { sh_x[SW(i)] = j1; sh_y[SW(j1)] = i; }
      if (i0 >= 0) {
        if (strict) {
          k--;
          if (tid == 0) sh_free[k] = i0;  // reprocess immediately
        } else {
          if (tid == 0) sh_free[nf] = i0;  // next pass
          nf++;
        }
      }
    }
    if (k < prv) {  // guard tripped (pathological): append remainder, SAP handles them
      for (int t = k; t < prv; ++t) {
        if (tid == 0) sh_free[nf] = sh_free[t];
        nf++;
      }
    }
  }
  __syncthreads();

  // ---- u from complementary slackness (exact f64): tight matched edges ----
  double myV[8];
#pragma unroll
  for (int q = 0; q < 8; ++q) {
    const int row = tid * 8 + q;
    const int xr = sh_x[SW(row)];
    double uu = 0.0;
    if (xr >= 0) uu = (double)cost[(size_t)row * NN + xr] - sh_v[SW(xr)];
    sh_u[SW(row)] = uu;
    myV[q] = sh_v[SW(tid * 8 + q)];
  }
  __syncthreads();

  // ---- 4. SAP phases for remaining free rows (Round-3 body, warm-started) ----
  for (int ff = 0; ff < nf; ++ff) {
    const int cur_row = sh_free[ff];

    double selv[8];   // current shortest (INF once in SC); reduce input
    double vAdj[8];   // myV, poisoned to -INF when col enters SC
    double frz[8];    // frozen shortest at SC-add time (= minv then)
    int myPath[8];
    unsigned pl[8];   // payload: (q<<10) | (row4col[col]+1)  (phase-constant)
#pragma unroll
    for (int q = 0; q < 8; ++q) {
      selv[q] = INF;
      vAdj[q] = myV[q];
      frz[q] = 0.0;
      myPath[q] = 0;
    }
#pragma unroll
    for (int q = 0; q < 8; ++q)
      pl[q] = ((unsigned)q << 10) | (unsigned)(sh_y[SW(tid * 8 + q)] + 1);

    unsigned scMask = 0, srMask = 0;
    int i = cur_row;     // uniform
    double minv = 0.0;   // uniform
    int sink = -1;       // uniform
    int pendQ = -1, pendLane = 0;
    int guard = 0;

    while (++guard <= NN + 2) {
      if ((i >> 3) == tid) srMask |= 1u << (i & 7);
      // dependent loads first; bookkeeping hides in their shadow
      const float4 c0 = *(const float4*)(cost + (size_t)i * NN + tid * 8);
      const float4 c1 = *(const float4*)(cost + (size_t)i * NN + tid * 8 + 4);
      const double u_i = sh_u[SW(i)];
      if (pendQ >= 0) {
        const bool me = (tid == pendLane);
#define APPLY_SC(K)                                                     \
        if (pendQ == K) {                                               \
          if (me) {                                                     \
            selv[K] = INF; vAdj[K] = -INF; frz[K] = minv;               \
            scMask |= 1u << K;                                          \
          }                                                             \
        }
        APPLY_SC(0) APPLY_SC(1) APPLY_SC(2) APPLY_SC(3)
        APPLY_SC(4) APPLY_SC(5) APPLY_SC(6) APPLY_SC(7)
#undef APPLY_SC
      }
      const float cf[8] = {c0.x, c0.y, c0.z, c0.w, c1.x, c1.y, c1.z, c1.w};
#pragma unroll
      for (int q = 0; q < 8; ++q) {
        const double r = ((minv + (double)cf[q]) - u_i) - vAdj[q];
        const bool cnd = r < selv[q];
        selv[q] = fmin(selv[q], r);
        myPath[q] = cnd ? i : myPath[q];
      }
      // per-lane tournament over 8 candidates (ties keep lowest q)
      const bool t01 = selv[1] < selv[0];
      double v01 = t01 ? selv[1] : selv[0]; unsigned p01 = t01 ? pl[1] : pl[0];
      const bool t23 = selv[3] < selv[2];
      double v23 = t23 ? selv[3] : selv[2]; unsigned p23 = t23 ? pl[3] : pl[2];
      const bool t45 = selv[5] < selv[4];
      double v45 = t45 ? selv[5] : selv[4]; unsigned p45 = t45 ? pl[5] : pl[4];
      const bool t67 = selv[7] < selv[6];
      double v67 = t67 ? selv[7] : selv[6]; unsigned p67 = t67 ? pl[7] : pl[6];
      const bool ta = v23 < v01;
      const double vab = ta ? v23 : v01; const unsigned pab = ta ? p23 : p01;
      const bool tb = v67 < v45;
      const double vcd = tb ? v67 : v45; const unsigned pcd = tb ? p67 : p45;
      const bool tc = vcd < vab;
      const double lv = tc ? vcd : vab; const unsigned lp = tc ? pcd : pab;
      // exact cross-lane argmin via sortable key
      const unsigned long long kk = f64key(lv);
      const unsigned hi = (unsigned)(kk >> 32);
      const unsigned lo = (unsigned)kk;
      const unsigned minhi = wave_min_u32(hi);
      unsigned long long bal = __ballot(hi == minhi);
      int srcLane;
      if (__popcll(bal) == 1) {
        srcLane = __ffsll(bal) - 1;
      } else {
        const unsigned lo2 = (hi == minhi) ? lo : 0xFFFFFFFFu;
        const unsigned minlo = wave_min_u32(lo2);
        bal = __ballot((hi == minhi) && (lo == minlo));
        srcLane = __ffsll(bal) - 1;
      }
      minv = readlane_f64(lv, srcLane);
      const unsigned pw = (unsigned)__builtin_amdgcn_readlane((int)lp, srcLane);
      const int qb = (int)(pw >> 10);
      const int r4 = (int)(pw & 0x3FFu) - 1;
      if (r4 < 0) {  // unmatched column: sink (its SC-add is a dual no-op)
        sink = srcLane * 8 + qb;
        break;
      }
      i = r4;
      pendQ = qb;
      pendLane = srcLane;
    }

    if (sink >= 0) {
      // publish frozen shortest + path (only SC cols are ever read back)
#pragma unroll
      for (int q = 0; q < 8; ++q) {
        sh_shortest[SW(tid * 8 + q)] = frz[q];
        sh_path[SW(tid * 8 + q)] = myPath[q];
      }
      __syncthreads();
      // dual updates (before augmentation)
#pragma unroll
      for (int q = 0; q < 8; ++q) {
        const int row = tid * 8 + q;
        if (row == cur_row) {
          sh_u[SW(row)] += minv;
        } else if (srMask & (1u << q)) {
          sh_u[SW(row)] += minv - sh_shortest[SW(sh_x[SW(row)])];
        }
        if (scMask & (1u << q)) myV[q] -= minv - frz[q];
      }
      __syncthreads();
      // augment along the alternating path (short chain, lane 0)
      if (tid == 0) {
        int j = sink;
        while (true) {
          const int pi = sh_path[SW(j)];
          sh_y[SW(j)] = pi;
          const int tmp = sh_x[SW(pi)];
          sh_x[SW(pi)] = j;
          j = tmp;
          if (pi == cur_row) break;
        }
      }
      __syncthreads();
    }
  }

#pragma unroll
  for (int q = 0; q < 8; ++q) {
    const int row = tid * 8 + q;
    outp[(size_t)row * NN + sh_x[SW(row)]] = 1.0f;
  }
}

extern "C" void kernel_launch(void* const* d_in, const int* in_sizes, int n_in,
                              void* d_out, int out_size, void* d_ws, size_t ws_size,
                              hipStream_t stream) {
  const float* un1 = (const float*)d_in[0];
  const float* un2 = (const float*)d_in[1];
  const float* un3 = (const float*)d_in[2];
  float* out = (float*)d_out;

  float* cost = (float*)d_ws;                       // 3 * 512 * 512 floats
  float* scales = cost + (size_t)3 * NN * NN;       // 3 * 512 floats

  hipMemsetAsync(d_out, 0, (size_t)out_size * sizeof(float), stream);

  norm_kernel<<<dim3(NN, 3), 256, 0, stream>>>(un1, un2, un3, scales);
  cost_gemm_kernel<<<dim3(NN / 64, NN / 64, 3), 256, 0, stream>>>(un1, un2, un3, scales, cost);
  lap_kernel<<<3, 64, 0, stream>>>(cost, out);
}

// Round 5
// 6079.957 us; speedup vs baseline: 1.8537x; 1.8537x over previous
//
#include <hip/hip_runtime.h>
#include <math.h>

#define NN 512
#define DD 8192

// ---------------- row-norm scales: scale[m][r] = 1 / max(||row||, 1e-6) ----------------
__global__ __launch_bounds__(256) void norm_kernel(
    const float* __restrict__ a0, const float* __restrict__ a1,
    const float* __restrict__ a2, float* __restrict__ scales) {
  const float* mats[3] = {a0, a1, a2};
  const int m = blockIdx.y;
  const int row = blockIdx.x;
  const float* x = mats[m] + (size_t)row * DD;
  const int tid = threadIdx.x;
  float s = 0.f;
  for (int k = tid * 4; k < DD; k += 256 * 4) {
    const float4 v = *(const float4*)(x + k);
    s += v.x * v.x + v.y * v.y + v.z * v.z + v.w * v.w;
  }
#pragma unroll
  for (int off = 32; off > 0; off >>= 1) s += __shfl_down(s, off);
  __shared__ float ws[4];
  if ((tid & 63) == 0) ws[tid >> 6] = s;
  __syncthreads();
  if (tid == 0) {
    const float t = ws[0] + ws[1] + ws[2] + ws[3];
    scales[m * NN + row] = 1.0f / fmaxf(sqrtf(t), 1e-6f);
  }
}

// ---------------- cost_p = 1 - (A B^T) * sa * sb, p: (0:1->2, 1:2->3, 2:3->1) ----------
__global__ __launch_bounds__(256) void cost_gemm_kernel(
    const float* __restrict__ a0, const float* __restrict__ a1,
    const float* __restrict__ a2, const float* __restrict__ scales,
    float* __restrict__ cost_all) {
  const float* mats[3] = {a0, a1, a2};
  const int p = blockIdx.z;
  const int pA = p, pB = (p + 1) % 3;
  const float* A = mats[pA];
  const float* B = mats[pB];
  float* C = cost_all + (size_t)p * NN * NN;

  __shared__ float lds_a[32 * 64];
  __shared__ float lds_b[32 * 64];

  const int tid = threadIdx.x;
  const int rowBase = blockIdx.y * 64;
  const int colBase = blockIdx.x * 64;

  const int lr = tid & 63;   // row within tile for staging
  const int lq = tid >> 6;   // 0..3

  const float* Arow = A + (size_t)(rowBase + lr) * DD;
  const float* Brow = B + (size_t)(colBase + lr) * DD;

  float acc[4][4];
#pragma unroll
  for (int i = 0; i < 4; ++i)
#pragma unroll
    for (int j = 0; j < 4; ++j) acc[i][j] = 0.f;

  const int tx = tid & 15, ty = tid >> 4;

  for (int kb = 0; kb < DD; kb += 32) {
#pragma unroll
    for (int qq = 0; qq < 2; ++qq) {
      const int q = lq + qq * 4;  // 0..7, covers k offsets q*4..q*4+3
      const float4 av = *(const float4*)(Arow + kb + q * 4);
      const float4 bv = *(const float4*)(Brow + kb + q * 4);
      lds_a[(q * 4 + 0) * 64 + lr] = av.x;
      lds_a[(q * 4 + 1) * 64 + lr] = av.y;
      lds_a[(q * 4 + 2) * 64 + lr] = av.z;
      lds_a[(q * 4 + 3) * 64 + lr] = av.w;
      lds_b[(q * 4 + 0) * 64 + lr] = bv.x;
      lds_b[(q * 4 + 1) * 64 + lr] = bv.y;
      lds_b[(q * 4 + 2) * 64 + lr] = bv.z;
      lds_b[(q * 4 + 3) * 64 + lr] = bv.w;
    }
    __syncthreads();
#pragma unroll
    for (int k = 0; k < 32; ++k) {
      const float4 a4 = *(const float4*)(&lds_a[k * 64 + ty * 4]);
      const float4 b4 = *(const float4*)(&lds_b[k * 64 + tx * 4]);
      const float as0[4] = {a4.x, a4.y, a4.z, a4.w};
      const float bs0[4] = {b4.x, b4.y, b4.z, b4.w};
#pragma unroll
      for (int ii = 0; ii < 4; ++ii)
#pragma unroll
        for (int jj = 0; jj < 4; ++jj)
          acc[ii][jj] = fmaf(as0[ii], bs0[jj], acc[ii][jj]);
    }
    __syncthreads();
  }

#pragma unroll
  for (int ii = 0; ii < 4; ++ii) {
    const int gr = rowBase + ty * 4 + ii;
    const float sa = scales[pA * NN + gr];
#pragma unroll
    for (int jj = 0; jj < 4; ++jj) {
      const int gc = colBase + tx * 4 + jj;
      const float sb = scales[pB * NN + gc];
      C[gr * NN + gc] = 1.0f - acc[ii][jj] * sa * sb;
    }
  }
}

// ---------------- exact LAP: column-reduction warm start + SAP, one wave -------------
// Lane t owns columns/rows 8t..8t+7. Warm start is EXACTLY dual-feasible (no ulp
// concerns): v[j]=min_i c[i][j], u=0, matched edges tight by construction. SAP phases
// (Round-3 body) run only for the ~37% of rows left free. NO reduction transfer / ARR
// (Round-4 lesson: auction-style bidding thrashes on concentrated cosine costs).
// Final assignment = unique optimum = reference output.

// bijective LDS index swizzle: owner-lane accesses (stride 8) become conflict-free
__device__ __forceinline__ int SW(int c) { return ((c & 7) << 6) | (c >> 3); }

// full-wave (64-lane) u32 min via DPP; returns broadcast scalar
__device__ __forceinline__ unsigned wave_min_u32(unsigned x) {
  int t;
  t = __builtin_amdgcn_update_dpp((int)x, (int)x, 0x111, 0xf, 0xf, false);  // row_shr:1
  x = ((unsigned)t < x) ? (unsigned)t : x;
  t = __builtin_amdgcn_update_dpp((int)x, (int)x, 0x112, 0xf, 0xf, false);  // row_shr:2
  x = ((unsigned)t < x) ? (unsigned)t : x;
  t = __builtin_amdgcn_update_dpp((int)x, (int)x, 0x114, 0xf, 0xf, false);  // row_shr:4
  x = ((unsigned)t < x) ? (unsigned)t : x;
  t = __builtin_amdgcn_update_dpp((int)x, (int)x, 0x118, 0xf, 0xf, false);  // row_shr:8
  x = ((unsigned)t < x) ? (unsigned)t : x;
  t = __builtin_amdgcn_update_dpp((int)x, (int)x, 0x142, 0xf, 0xf, false);  // row_bcast:15
  x = ((unsigned)t < x) ? (unsigned)t : x;
  t = __builtin_amdgcn_update_dpp((int)x, (int)x, 0x143, 0xf, 0xf, false);  // row_bcast:31
  x = ((unsigned)t < x) ? (unsigned)t : x;
  return (unsigned)__builtin_amdgcn_readlane((int)x, 63);
}

__device__ __forceinline__ double readlane_f64(double x, int lane) {
  const long long b = __double_as_longlong(x);
  const int lo = __builtin_amdgcn_readlane((int)(b & 0xffffffffLL), lane);
  const int hi = __builtin_amdgcn_readlane((int)(b >> 32), lane);
  return __longlong_as_double(((long long)hi << 32) | (unsigned long long)(unsigned)lo);
}

__device__ __forceinline__ unsigned long long f64key(double x) {
  const long long b = __double_as_longlong(x);
  return (b < 0) ? ~(unsigned long long)b
                 : ((unsigned long long)b | 0x8000000000000000ULL);
}

__global__ __launch_bounds__(64) void lap_kernel(
    const float* __restrict__ cost_all, float* __restrict__ out) {
  const int p = blockIdx.x;
  const float* cost = cost_all + (size_t)p * NN * NN;
  float* outp = out + (size_t)p * NN * NN;
  const int tid = threadIdx.x;  // 0..63

  __shared__ double sh_u[NN];        // u[row] at SW(row)
  __shared__ double sh_shortest[NN]; // frozen shortest[col] at SW(col)
  __shared__ int sh_path[NN];        // path[col] at SW(col)
  __shared__ int sh_x[NN];           // col4row[row] at SW(row)
  __shared__ int sh_y[NN];           // row4col[col] at SW(col)
  __shared__ int sh_free[NN];        // free-row work list (plain indexing)

  const double INF = __builtin_inf();

#pragma unroll
  for (int q = 0; q < 8; ++q) {
    const int e = tid * 8 + q;
    sh_x[SW(e)] = -1;
    sh_y[SW(e)] = -1;
    sh_u[SW(e)] = 0.0;  // exact: all u are 0 in the colred state
  }
  __syncthreads();

  // ---- 1. column reduction: v[j] = min_i c[i][j]; assign argmin rows (largest j
  //         wins on collision == lap.c descending-j scan). Streaming, no dep chain. ----
  float colv[8];
  int imin[8];
#pragma unroll
  for (int q = 0; q < 8; ++q) { colv[q] = __builtin_inff(); imin[q] = 0; }
  for (int i = 0; i < NN; i += 2) {
    const float4 a0 = *(const float4*)(cost + (size_t)i * NN + tid * 8);
    const float4 a1 = *(const float4*)(cost + (size_t)i * NN + tid * 8 + 4);
    const float4 b0 = *(const float4*)(cost + (size_t)(i + 1) * NN + tid * 8);
    const float4 b1 = *(const float4*)(cost + (size_t)(i + 1) * NN + tid * 8 + 4);
    const float fa[8] = {a0.x, a0.y, a0.z, a0.w, a1.x, a1.y, a1.z, a1.w};
    const float fb[8] = {b0.x, b0.y, b0.z, b0.w, b1.x, b1.y, b1.z, b1.w};
#pragma unroll
    for (int q = 0; q < 8; ++q) {
      if (fa[q] < colv[q]) { colv[q] = fa[q]; imin[q] = i; }
      if (fb[q] < colv[q]) { colv[q] = fb[q]; imin[q] = i + 1; }
    }
  }
#pragma unroll
  for (int q = 0; q < 8; ++q) atomicMax(&sh_x[SW(imin[q])], tid * 8 + q);
  __syncthreads();
#pragma unroll
  for (int q = 0; q < 8; ++q) {
    const int j = tid * 8 + q;
    sh_y[SW(j)] = (sh_x[SW(imin[q])] == j) ? imin[q] : -1;
  }
  // v lives only in registers: owner-lane copy (matched edges are exactly tight:
  // c[imin[q]][j] - v[j] = 0; reduced costs >= 0 exactly since v[j] = column min)
  double myV[8];
#pragma unroll
  for (int q = 0; q < 8; ++q) myV[q] = (double)colv[q];
  __syncthreads();

  // ---- build free-row list (ascending row order within each q-group) ----
  int numfree = 0;
  for (int q0 = 0; q0 < 8; ++q0) {
    const int row = tid * 8 + q0;
    const bool fr = (sh_x[SW(row)] < 0);
    const unsigned long long mask = __ballot(fr);
    if (fr) {
      const int pos = numfree + (int)__popcll(mask & ((1ull << tid) - 1ull));
      sh_free[pos] = row;
    }
    numfree += (int)__popcll(mask);
  }
  __syncthreads();

  // ---- 2. SAP phases for free rows (Round-3 body, warm-started) ----
  for (int ff = 0; ff < numfree; ++ff) {
    const int cur_row = sh_free[ff];

    double selv[8];   // current shortest (INF once in SC); reduce input
    double vAdj[8];   // myV, poisoned to -INF when col enters SC
    double frz[8];    // frozen shortest at SC-add time (= minv then)
    int myPath[8];
    unsigned pl[8];   // payload: (q<<10) | (row4col[col]+1)  (phase-constant)
#pragma unroll
    for (int q = 0; q < 8; ++q) {
      selv[q] = INF;
      vAdj[q] = myV[q];
      frz[q] = 0.0;
      myPath[q] = 0;
    }
#pragma unroll
    for (int q = 0; q < 8; ++q)
      pl[q] = ((unsigned)q << 10) | (unsigned)(sh_y[SW(tid * 8 + q)] + 1);

    unsigned scMask = 0, srMask = 0;
    int i = cur_row;     // uniform
    double minv = 0.0;   // uniform
    int sink = -1;       // uniform
    int pendQ = -1, pendLane = 0;
    int guard = 0;

    while (++guard <= NN + 2) {
      if ((i >> 3) == tid) srMask |= 1u << (i & 7);
      // dependent loads first; all bookkeeping below hides in their shadow
      const float4 c0 = *(const float4*)(cost + (size_t)i * NN + tid * 8);
      const float4 c1 = *(const float4*)(cost + (size_t)i * NN + tid * 8 + 4);
      const double u_i = sh_u[SW(i)];
      if (pendQ >= 0) {
        const bool me = (tid == pendLane);
#define APPLY_SC(K)                                                     \
        if (pendQ == K) {                                               \
          if (me) {                                                     \
            selv[K] = INF; vAdj[K] = -INF; frz[K] = minv;               \
            scMask |= 1u << K;                                          \
          }                                                             \
        }
        APPLY_SC(0) APPLY_SC(1) APPLY_SC(2) APPLY_SC(3)
        APPLY_SC(4) APPLY_SC(5) APPLY_SC(6) APPLY_SC(7)
#undef APPLY_SC
      }
      // load-independent bases, computed in the load shadow:
      // r = cf[q] + ((minv - u_i) - vAdj[q])   [re-associated vs reference; final
      // matching is the unique optimum, margins >> accumulated f64 rounding]
      const double mu = minv - u_i;
      double base[8];
#pragma unroll
      for (int q = 0; q < 8; ++q) base[q] = mu - vAdj[q];  // SC cols: +INF
      const float cf[8] = {c0.x, c0.y, c0.z, c0.w, c1.x, c1.y, c1.z, c1.w};
#pragma unroll
      for (int q = 0; q < 8; ++q) {
        const double r = (double)cf[q] + base[q];
        const bool cnd = r < selv[q];
        selv[q] = fmin(selv[q], r);
        myPath[q] = cnd ? i : myPath[q];
      }
      // per-lane tournament over 8 candidates (ties keep lowest q)
      const bool t01 = selv[1] < selv[0];
      double v01 = t01 ? selv[1] : selv[0]; unsigned p01 = t01 ? pl[1] : pl[0];
      const bool t23 = selv[3] < selv[2];
      double v23 = t23 ? selv[3] : selv[2]; unsigned p23 = t23 ? pl[3] : pl[2];
      const bool t45 = selv[5] < selv[4];
      double v45 = t45 ? selv[5] : selv[4]; unsigned p45 = t45 ? pl[5] : pl[4];
      const bool t67 = selv[7] < selv[6];
      double v67 = t67 ? selv[7] : selv[6]; unsigned p67 = t67 ? pl[7] : pl[6];
      const bool ta = v23 < v01;
      const double vab = ta ? v23 : v01; const unsigned pab = ta ? p23 : p01;
      const bool tb = v67 < v45;
      const double vcd = tb ? v67 : v45; const unsigned pcd = tb ? p67 : p45;
      const bool tc = vcd < vab;
      const double lv = tc ? vcd : vab; const unsigned lp = tc ? pcd : pab;
      // exact cross-lane argmin via sortable key
      const unsigned long long kk = f64key(lv);
      const unsigned hi = (unsigned)(kk >> 32);
      const unsigned lo = (unsigned)kk;
      const unsigned minhi = wave_min_u32(hi);
      unsigned long long bal = __ballot(hi == minhi);
      int srcLane;
      if (__popcll(bal) == 1) {
        srcLane = __ffsll(bal) - 1;
      } else {
        const unsigned lo2 = (hi == minhi) ? lo : 0xFFFFFFFFu;
        const unsigned minlo = wave_min_u32(lo2);
        bal = __ballot((hi == minhi) && (lo == minlo));
        srcLane = __ffsll(bal) - 1;  // lowest lane = smallest column on exact ties
      }
      minv = readlane_f64(lv, srcLane);
      const unsigned pw = (unsigned)__builtin_amdgcn_readlane((int)lp, srcLane);
      const int qb = (int)(pw >> 10);
      const int r4 = (int)(pw & 0x3FFu) - 1;
      if (r4 < 0) {  // unmatched column: sink (its SC-add is a dual no-op)
        sink = srcLane * 8 + qb;
        break;
      }
      i = r4;
      pendQ = qb;
      pendLane = srcLane;
    }

    if (sink >= 0) {
      // publish frozen shortest + path (only SC cols are ever read back)
#pragma unroll
      for (int q = 0; q < 8; ++q) {
        sh_shortest[SW(tid * 8 + q)] = frz[q];
        sh_path[SW(tid * 8 + q)] = myPath[q];
      }
      __syncthreads();
      // dual updates (before augmentation)
#pragma unroll
      for (int q = 0; q < 8; ++q) {
        const int row = tid * 8 + q;
        if (row == cur_row) {
          sh_u[SW(row)] += minv;
        } else if (srMask & (1u << q)) {
          sh_u[SW(row)] += minv - sh_shortest[SW(sh_x[SW(row)])];
        }
        if (scMask & (1u << q)) myV[q] -= minv - frz[q];
      }
      __syncthreads();
      // augment along the alternating path (short chain, lane 0)
      if (tid == 0) {
        int j = sink;
        while (true) {
          const int pi = sh_path[SW(j)];
          sh_y[SW(j)] = pi;
          const int tmp = sh_x[SW(pi)];
          sh_x[SW(pi)] = j;
          j = tmp;
          if (pi == cur_row) break;
        }
      }
      __syncthreads();
    }
  }

#pragma unroll
  for (int q = 0; q < 8; ++q) {
    const int row = tid * 8 + q;
    const int xc = sh_x[SW(row)];
    if (xc >= 0) outp[(size_t)row * NN + xc] = 1.0f;
  }
}

extern "C" void kernel_launch(void* const* d_in, const int* in_sizes, int n_in,
                              void* d_out, int out_size, void* d_ws, size_t ws_size,
                              hipStream_t stream) {
  const float* un1 = (const float*)d_in[0];
  const float* un2 = (const float*)d_in[1];
  const float* un3 = (const float*)d_in[2];
  float* out = (float*)d_out;

  float* cost = (float*)d_ws;                       // 3 * 512 * 512 floats
  float* scales = cost + (size_t)3 * NN * NN;       // 3 * 512 floats

  hipMemsetAsync(d_out, 0, (size_t)out_size * sizeof(float), stream);

  norm_kernel<<<dim3(NN, 3), 256, 0, stream>>>(un1, un2, un3, scales);
  cost_gemm_kernel<<<dim3(NN / 64, NN / 64, 3), 256, 0, stream>>>(un1, un2, un3, scales, cost);
  lap_kernel<<<3, 64, 0, stream>>>(cost, out);
}

// Round 6
// 5883.266 us; speedup vs baseline: 1.9156x; 1.0334x over previous
//
#include <hip/hip_runtime.h>
#include <math.h>

#define NN 512
#define DD 8192

// ---------------- row-norm scales: scale[m][r] = 1 / max(||row||, 1e-6) ----------------
__global__ __launch_bounds__(256) void norm_kernel(
    const float* __restrict__ a0, const float* __restrict__ a1,
    const float* __restrict__ a2, float* __restrict__ scales) {
  const float* mats[3] = {a0, a1, a2};
  const int m = blockIdx.y;
  const int row = blockIdx.x;
  const float* x = mats[m] + (size_t)row * DD;
  const int tid = threadIdx.x;
  float s = 0.f;
  for (int k = tid * 4; k < DD; k += 256 * 4) {
    const float4 v = *(const float4*)(x + k);
    s += v.x * v.x + v.y * v.y + v.z * v.z + v.w * v.w;
  }
#pragma unroll
  for (int off = 32; off > 0; off >>= 1) s += __shfl_down(s, off);
  __shared__ float ws[4];
  if ((tid & 63) == 0) ws[tid >> 6] = s;
  __syncthreads();
  if (tid == 0) {
    const float t = ws[0] + ws[1] + ws[2] + ws[3];
    scales[m * NN + row] = 1.0f / fmaxf(sqrtf(t), 1e-6f);
  }
}

// ---------------- cost_p = 1 - (A B^T) * sa * sb, p: (0:1->2, 1:2->3, 2:3->1) ----------
// BK=64 (was 32): halves barrier/staging step count; LDS 2x16KB.
__global__ __launch_bounds__(256) void cost_gemm_kernel(
    const float* __restrict__ a0, const float* __restrict__ a1,
    const float* __restrict__ a2, const float* __restrict__ scales,
    float* __restrict__ cost_all) {
  const float* mats[3] = {a0, a1, a2};
  const int p = blockIdx.z;
  const int pA = p, pB = (p + 1) % 3;
  const float* A = mats[pA];
  const float* B = mats[pB];
  float* C = cost_all + (size_t)p * NN * NN;

  __shared__ float lds_a[64 * 64];  // [k][row]
  __shared__ float lds_b[64 * 64];

  const int tid = threadIdx.x;
  const int rowBase = blockIdx.y * 64;
  const int colBase = blockIdx.x * 64;

  const int lr = tid & 63;   // row within tile for staging
  const int lq = tid >> 6;   // 0..3

  const float* Arow = A + (size_t)(rowBase + lr) * DD;
  const float* Brow = B + (size_t)(colBase + lr) * DD;

  float acc[4][4];
#pragma unroll
  for (int i = 0; i < 4; ++i)
#pragma unroll
    for (int j = 0; j < 4; ++j) acc[i][j] = 0.f;

  const int tx = tid & 15, ty = tid >> 4;

  for (int kb = 0; kb < DD; kb += 64) {
#pragma unroll
    for (int qq = 0; qq < 4; ++qq) {
      const int q = lq + qq * 4;  // 0..15, covers k offsets q*4..q*4+3
      const float4 av = *(const float4*)(Arow + kb + q * 4);
      const float4 bv = *(const float4*)(Brow + kb + q * 4);
      lds_a[(q * 4 + 0) * 64 + lr] = av.x;
      lds_a[(q * 4 + 1) * 64 + lr] = av.y;
      lds_a[(q * 4 + 2) * 64 + lr] = av.z;
      lds_a[(q * 4 + 3) * 64 + lr] = av.w;
      lds_b[(q * 4 + 0) * 64 + lr] = bv.x;
      lds_b[(q * 4 + 1) * 64 + lr] = bv.y;
      lds_b[(q * 4 + 2) * 64 + lr] = bv.z;
      lds_b[(q * 4 + 3) * 64 + lr] = bv.w;
    }
    __syncthreads();
#pragma unroll 8
    for (int k = 0; k < 64; ++k) {
      const float4 a4 = *(const float4*)(&lds_a[k * 64 + ty * 4]);
      const float4 b4 = *(const float4*)(&lds_b[k * 64 + tx * 4]);
      const float as0[4] = {a4.x, a4.y, a4.z, a4.w};
      const float bs0[4] = {b4.x, b4.y, b4.z, b4.w};
#pragma unroll
      for (int ii = 0; ii < 4; ++ii)
#pragma unroll
        for (int jj = 0; jj < 4; ++jj)
          acc[ii][jj] = fmaf(as0[ii], bs0[jj], acc[ii][jj]);
    }
    __syncthreads();
  }

#pragma unroll
  for (int ii = 0; ii < 4; ++ii) {
    const int gr = rowBase + ty * 4 + ii;
    const float sa = scales[pA * NN + gr];
#pragma unroll
    for (int jj = 0; jj < 4; ++jj) {
      const int gc = colBase + tx * 4 + jj;
      const float sb = scales[pB * NN + gc];
      C[gr * NN + gc] = 1.0f - acc[ii][jj] * sa * sb;
    }
  }
}

// ---------------- exact JV shortest-augmenting-path LAP, ONE WAVE per problem ----------
// Round-3 cold-start structure (empirically fastest: warm starts conserve total
// inner iterations, Round-4/5 evidence). Lane t owns columns/rows 8t..8t+7. Zero LDS
// ops in the inner loop; SC-exclusion via vAdj=-INF poison; relax bases precomputed
// in the load shadow. float64 duals; final assignment = unique optimum = reference.

// bijective LDS index swizzle: owner-lane accesses (stride 8) become conflict-free
__device__ __forceinline__ int SW(int c) { return ((c & 7) << 6) | (c >> 3); }

// full-wave (64-lane) u32 min via DPP; returns broadcast scalar
__device__ __forceinline__ unsigned wave_min_u32(unsigned x) {
  int t;
  t = __builtin_amdgcn_update_dpp((int)x, (int)x, 0x111, 0xf, 0xf, false);  // row_shr:1
  x = ((unsigned)t < x) ? (unsigned)t : x;
  t = __builtin_amdgcn_update_dpp((int)x, (int)x, 0x112, 0xf, 0xf, false);  // row_shr:2
  x = ((unsigned)t < x) ? (unsigned)t : x;
  t = __builtin_amdgcn_update_dpp((int)x, (int)x, 0x114, 0xf, 0xf, false);  // row_shr:4
  x = ((unsigned)t < x) ? (unsigned)t : x;
  t = __builtin_amdgcn_update_dpp((int)x, (int)x, 0x118, 0xf, 0xf, false);  // row_shr:8
  x = ((unsigned)t < x) ? (unsigned)t : x;
  t = __builtin_amdgcn_update_dpp((int)x, (int)x, 0x142, 0xf, 0xf, false);  // row_bcast:15
  x = ((unsigned)t < x) ? (unsigned)t : x;
  t = __builtin_amdgcn_update_dpp((int)x, (int)x, 0x143, 0xf, 0xf, false);  // row_bcast:31
  x = ((unsigned)t < x) ? (unsigned)t : x;
  return (unsigned)__builtin_amdgcn_readlane((int)x, 63);
}

__device__ __forceinline__ double readlane_f64(double x, int lane) {
  const long long b = __double_as_longlong(x);
  const int lo = __builtin_amdgcn_readlane((int)(b & 0xffffffffLL), lane);
  const int hi = __builtin_amdgcn_readlane((int)(b >> 32), lane);
  return __longlong_as_double(((long long)hi << 32) | (unsigned long long)(unsigned)lo);
}

__device__ __forceinline__ unsigned long long f64key(double x) {
  const long long b = __double_as_longlong(x);
  return (b < 0) ? ~(unsigned long long)b
                 : ((unsigned long long)b | 0x8000000000000000ULL);
}

__global__ __launch_bounds__(64) void lap_kernel(
    const float* __restrict__ cost_all, float* __restrict__ out) {
  const int p = blockIdx.x;
  const float* cost = cost_all + (size_t)p * NN * NN;
  float* outp = out + (size_t)p * NN * NN;
  const int tid = threadIdx.x;  // 0..63

  __shared__ double sh_u[NN];        // u[row] at SW(row)
  __shared__ double sh_shortest[NN]; // frozen shortest[col] at SW(col)
  __shared__ int sh_path[NN];        // path[col] at SW(col)
  __shared__ int sh_x[NN];           // col4row[row] at SW(row)
  __shared__ int sh_y[NN];           // row4col[col] at SW(col)

  const double INF = __builtin_inf();

#pragma unroll
  for (int q = 0; q < 8; ++q) {
    const int e = tid * 8 + q;
    sh_x[SW(e)] = -1;
    sh_y[SW(e)] = -1;
    sh_u[SW(e)] = 0.0;
  }
  double myV[8];
#pragma unroll
  for (int q = 0; q < 8; ++q) myV[q] = 0.0;  // v[8*tid+q], owner-only
  __syncthreads();

  for (int cur_row = 0; cur_row < NN; ++cur_row) {
    double selv[8];   // current shortest (INF once in SC); reduce input
    double vAdj[8];   // myV, poisoned to -INF when col enters SC
    double frz[8];    // frozen shortest at SC-add time (= minv then)
    int myPath[8];
    unsigned pl[8];   // payload: (q<<10) | (row4col[col]+1)  (phase-constant)
#pragma unroll
    for (int q = 0; q < 8; ++q) {
      selv[q] = INF;
      vAdj[q] = myV[q];
      frz[q] = 0.0;
      myPath[q] = 0;
    }
#pragma unroll
    for (int q = 0; q < 8; ++q)
      pl[q] = ((unsigned)q << 10) | (unsigned)(sh_y[SW(tid * 8 + q)] + 1);

    unsigned scMask = 0, srMask = 0;
    int i = cur_row;     // uniform
    double minv = 0.0;   // uniform
    int sink = -1;       // uniform
    int pendQ = -1, pendLane = 0;

    while (true) {
      // dependent loads first; all bookkeeping below hides in their shadow
      const float4 c0 = *(const float4*)(cost + (size_t)i * NN + tid * 8);
      const float4 c1 = *(const float4*)(cost + (size_t)i * NN + tid * 8 + 4);
      const double u_i = sh_u[SW(i)];
      if ((i >> 3) == tid) srMask |= 1u << (i & 7);
      if (pendQ >= 0) {
        const bool me = (tid == pendLane);
#define APPLY_SC(K)                                                     \
        if (pendQ == K) {                                               \
          if (me) {                                                     \
            selv[K] = INF; vAdj[K] = -INF; frz[K] = minv;               \
            scMask |= 1u << K;                                          \
          }                                                             \
        }
        APPLY_SC(0) APPLY_SC(1) APPLY_SC(2) APPLY_SC(3)
        APPLY_SC(4) APPLY_SC(5) APPLY_SC(6) APPLY_SC(7)
#undef APPLY_SC
      }
      // load-independent bases, computed in the load shadow:
      // r = cf[q] + ((minv - u_i) - vAdj[q])   [re-associated; final matching is the
      // unique optimum, margins >> accumulated f64 rounding]
      const double mu = minv - u_i;
      double base[8];
#pragma unroll
      for (int q = 0; q < 8; ++q) base[q] = mu - vAdj[q];  // SC cols: +INF
      const float cf[8] = {c0.x, c0.y, c0.z, c0.w, c1.x, c1.y, c1.z, c1.w};
#pragma unroll
      for (int q = 0; q < 8; ++q) {
        const double r = (double)cf[q] + base[q];
        const bool cnd = r < selv[q];
        selv[q] = fmin(selv[q], r);
        myPath[q] = cnd ? i : myPath[q];
      }
      // per-lane tournament over 8 candidates (ties keep lowest q)
      const bool t01 = selv[1] < selv[0];
      double v01 = t01 ? selv[1] : selv[0]; unsigned p01 = t01 ? pl[1] : pl[0];
      const bool t23 = selv[3] < selv[2];
      double v23 = t23 ? selv[3] : selv[2]; unsigned p23 = t23 ? pl[3] : pl[2];
      const bool t45 = selv[5] < selv[4];
      double v45 = t45 ? selv[5] : selv[4]; unsigned p45 = t45 ? pl[5] : pl[4];
      const bool t67 = selv[7] < selv[6];
      double v67 = t67 ? selv[7] : selv[6]; unsigned p67 = t67 ? pl[7] : pl[6];
      const bool ta = v23 < v01;
      const double vab = ta ? v23 : v01; const unsigned pab = ta ? p23 : p01;
      const bool tb = v67 < v45;
      const double vcd = tb ? v67 : v45; const unsigned pcd = tb ? p67 : p45;
      const bool tc = vcd < vab;
      const double lv = tc ? vcd : vab; const unsigned lp = tc ? pcd : pab;
      // exact cross-lane argmin via sortable key
      const unsigned long long kk = f64key(lv);
      const unsigned hi = (unsigned)(kk >> 32);
      const unsigned lo = (unsigned)kk;
      const unsigned minhi = wave_min_u32(hi);
      unsigned long long bal = __ballot(hi == minhi);
      int srcLane;
      if (__popcll(bal) == 1) {  // unique hi-key => unique global min (common case)
        srcLane = __ffsll(bal) - 1;
      } else {
        const unsigned lo2 = (hi == minhi) ? lo : 0xFFFFFFFFu;
        const unsigned minlo = wave_min_u32(lo2);
        bal = __ballot((hi == minhi) && (lo == minlo));
        srcLane = __ffsll(bal) - 1;  // lowest lane = smallest column on exact ties
      }
      // decode payload FIRST so the next iteration's loads (dep: i) issue before
      // the minv readlanes; minv is only needed in the next load's shadow
      const unsigned pw = (unsigned)__builtin_amdgcn_readlane((int)lp, srcLane);
      const int qb = (int)(pw >> 10);
      const int r4 = (int)(pw & 0x3FFu) - 1;
      minv = readlane_f64(lv, srcLane);
      if (r4 < 0) {  // unmatched column: sink (its SC-add is a dual no-op)
        sink = srcLane * 8 + qb;
        break;
      }
      i = r4;
      pendQ = qb;
      pendLane = srcLane;
    }

    // publish frozen shortest + path (only SC cols are ever read back)
#pragma unroll
    for (int q = 0; q < 8; ++q) {
      sh_shortest[SW(tid * 8 + q)] = frz[q];
      sh_path[SW(tid * 8 + q)] = myPath[q];
    }
    __syncthreads();
    // dual updates (before augmentation, matching reference)
#pragma unroll
    for (int q = 0; q < 8; ++q) {
      const int row = tid * 8 + q;
      if (row == cur_row) {
        sh_u[SW(row)] += minv;
      } else if (srMask & (1u << q)) {
        sh_u[SW(row)] += minv - sh_shortest[SW(sh_x[SW(row)])];
      }
      if (scMask & (1u << q)) myV[q] -= minv - frz[q];
    }
    __syncthreads();
    // augment along the alternating path (short chain, lane 0)
    if (tid == 0) {
      int j = sink;
      while (true) {
        const int pi = sh_path[SW(j)];
        sh_y[SW(j)] = pi;
        const int tmp = sh_x[SW(pi)];
        sh_x[SW(pi)] = j;
        j = tmp;
        if (pi == cur_row) break;
      }
    }
    __syncthreads();  // publish matching for next phase
  }

#pragma unroll
  for (int q = 0; q < 8; ++q) {
    const int row = tid * 8 + q;
    outp[(size_t)row * NN + sh_x[SW(row)]] = 1.0f;
  }
}

extern "C" void kernel_launch(void* const* d_in, const int* in_sizes, int n_in,
                              void* d_out, int out_size, void* d_ws, size_t ws_size,
                              hipStream_t stream) {
  const float* un1 = (const float*)d_in[0];
  const float* un2 = (const float*)d_in[1];
  const float* un3 = (const float*)d_in[2];
  float* out = (float*)d_out;

  float* cost = (float*)d_ws;                       // 3 * 512 * 512 floats
  float* scales = cost + (size_t)3 * NN * NN;       // 3 * 512 floats

  hipMemsetAsync(d_out, 0, (size_t)out_size * sizeof(float), stream);

  norm_kernel<<<dim3(NN, 3), 256, 0, stream>>>(un1, un2, un3, scales);
  cost_gemm_kernel<<<dim3(NN / 64, NN / 64, 3), 256, 0, stream>>>(un1, un2, un3, scales, cost);
  lap_kernel<<<3, 64, 0, stream>>>(cost, out);
}